// Round 1
// baseline (116.354 us; speedup 1.0000x reference)
//
#include <hip/hip_runtime.h>
#include <math.h>

#define BATCH 4
#define NPTS  8000
#define NCH   256
#define TILE  2000
#define QPB   32
#define SPLIT 8

// One block: 32 queries x 8 j-splits = 256 threads.
// Points staged in LDS tiles of 2000 float4 (x,y,z,|p|^2) = 32 KB.
// Each thread scans j = s, s+8, s+16, ... within the tile (LDS reads are
// 8 consecutive float4s broadcast across 8 query lanes -> conflict-free).
// Top-2 tracked with strict < (keeps lowest index on exact ties, matching
// jax.lax.top_k), then merged across the 8 split lanes with (d2, idx)
// lexicographic compares via __shfl_xor.
__global__ __launch_bounds__(256) void knn_mean_kernel(
    const float* __restrict__ points, const float* __restrict__ preds,
    float* __restrict__ out) {
  __shared__ float4 pts[TILE];
  __shared__ int nbr[QPB][2];

  const int t = threadIdx.x;
  const int b = blockIdx.y;
  const int ql = t >> 3;       // query slot within block: 0..31
  const int s = t & 7;         // j-split: 0..7
  const int qg = blockIdx.x * QPB + ql;

  const float* __restrict__ pb = points + (size_t)b * NPTS * 3;
  const float xi = pb[qg * 3 + 0];
  const float yi = pb[qg * 3 + 1];
  const float zi = pb[qg * 3 + 2];
  const float sqi = xi * xi + yi * yi + zi * zi;

  float b0 = INFINITY, b1 = INFINITY;
  int j0 = 0, j1 = 0;

  for (int tb = 0; tb < NPTS / TILE; ++tb) {
    const int base = tb * TILE;
    __syncthreads();  // protect LDS from previous tile's readers
    for (int p = t; p < TILE; p += 256) {
      const float x = pb[(base + p) * 3 + 0];
      const float y = pb[(base + p) * 3 + 1];
      const float z = pb[(base + p) * 3 + 2];
      pts[p] = make_float4(x, y, z, x * x + y * y + z * z);
    }
    __syncthreads();
    int j = base + s;
#pragma unroll 2
    for (int it = 0; it < TILE / SPLIT; ++it) {
      const float4 P = pts[s + it * SPLIT];
      const float dot = xi * P.x + yi * P.y + zi * P.z;
      const float d2 = (sqi + P.w) - 2.0f * dot;  // same formula as reference
      const bool c0 = d2 < b0;
      const bool c1 = d2 < b1;
      const float nb1 = c0 ? b0 : (c1 ? d2 : b1);
      const int nj1 = c0 ? j0 : (c1 ? j : j1);
      b0 = c0 ? d2 : b0;
      j0 = c0 ? j : j0;
      b1 = nb1;
      j1 = nj1;
      j += SPLIT;
    }
  }

  // Merge top-2 across the 8 split lanes (lanes ql*8 .. ql*8+7 in each wave).
#pragma unroll
  for (int m = 1; m < SPLIT; m <<= 1) {
    const float ob0 = __shfl_xor(b0, m);
    const int oj0 = __shfl_xor(j0, m);
    const float ob1 = __shfl_xor(b1, m);
    const int oj1 = __shfl_xor(j1, m);
    const bool afirst = (b0 < ob0) || (b0 == ob0 && j0 < oj0);
    const float w1 = afirst ? b1 : ob1;  // winner's second
    const int wj1 = afirst ? j1 : oj1;
    const float l0 = afirst ? ob0 : b0;  // loser's first
    const int lj0 = afirst ? oj0 : j0;
    b0 = afirst ? b0 : ob0;
    j0 = afirst ? j0 : oj0;
    const bool cfirst = (w1 < l0) || (w1 == l0 && wj1 < lj0);
    b1 = cfirst ? w1 : l0;
    j1 = cfirst ? wj1 : lj0;
  }

  if (s == 0) {
    nbr[ql][0] = j0;
    nbr[ql][1] = j1;
  }
  __syncthreads();

  // Gather + mean epilogue: one wave handles one query row at a time;
  // 64 lanes x float4 = 256 channels, fully coalesced.
  const int wave = t >> 6;
  const int lane = t & 63;
  const float* __restrict__ predb = preds + (size_t)b * NPTS * NCH;
  float* __restrict__ outb = out + (size_t)b * NPTS * NCH;
  for (int q = wave; q < QPB; q += 4) {
    const int a = nbr[q][0];
    const int c = nbr[q][1];
    const float4 va = ((const float4*)(predb + (size_t)a * NCH))[lane];
    const float4 vc = ((const float4*)(predb + (size_t)c * NCH))[lane];
    float4 r;
    r.x = 0.5f * (va.x + vc.x);
    r.y = 0.5f * (va.y + vc.y);
    r.z = 0.5f * (va.z + vc.z);
    r.w = 0.5f * (va.w + vc.w);
    ((float4*)(outb + (size_t)(blockIdx.x * QPB + q) * NCH))[lane] = r;
  }
}

extern "C" void kernel_launch(void* const* d_in, const int* in_sizes, int n_in,
                              void* d_out, int out_size, void* d_ws, size_t ws_size,
                              hipStream_t stream) {
  const float* points = (const float*)d_in[0];
  const float* preds = (const float*)d_in[1];
  // d_in[2] (k_vector) is unused: reference hardcodes k = 2.
  float* out = (float*)d_out;
  dim3 grid(NPTS / QPB, BATCH);
  knn_mean_kernel<<<grid, 256, 0, stream>>>(points, preds, out);
}